// Round 4
// baseline (206.930 us; speedup 1.0000x reference)
//
#include <hip/hip_runtime.h>

#define NUM_HEADS 16u

typedef float f32x4 __attribute__((ext_vector_type(4)));  // clang vector for nontemporal store

// ALiBi bias: out[((b*H + h)*S + i)*S + j] = -slopes[h] * |i - j|
// Write-BW-bound (1 GiB f32 out). Fill-kernel ceiling on this path: 6.4-6.6 TB/s.
// This round: zero-churn config. 2048 blocks (exactly fills 256 CU x 32 waves),
// each block owns one contiguous 64-row (512 KiB) region inside a single (b,h)
// image -> h/slope/base computed once per block; inner loop is d+=1.0f, ptr
// bump, 14 VALU, 2 nontemporal dwordx4 stores per thread. No div in the loop.
__global__ __launch_bounds__(256) void alibi_bias_kernel(
    const float* __restrict__ slopes,
    const int* __restrict__ seq_p,
    float* __restrict__ out,
    unsigned int n_total)
{
    const unsigned int S = (unsigned int)seq_p[0];
    const unsigned int rows_total = n_total / S;

    // Fast path: S==2048, rows divide evenly over blocks, block-region stays
    // inside one image (rpb | S). All uniform branches.
    if (S == 2048u &&
        rows_total * S == n_total &&
        (rows_total % gridDim.x) == 0u) {
        const unsigned int rpb = rows_total / gridDim.x;      // rows/block (64)
        if ((S % rpb) == 0u) {
            const unsigned int r0 = blockIdx.x * rpb;         // first global row
            const unsigned int i0 = r0 & (S - 1u);            // row within image
            const unsigned int h  = (r0 / S) & (NUM_HEADS - 1u);
            const float nslope = -slopes[h];

            const int j0 = (int)(threadIdx.x << 2);
            float d  = (float)((int)i0 - j0);                 // exact in f32
            float d2 = d - 1024.0f;                           // lane's 2nd float4
            f32x4* __restrict__ p =
                (f32x4*)(out + (size_t)r0 * (size_t)S) + threadIdx.x;

            #pragma unroll 4
            for (unsigned int r = 0; r < rpb; ++r) {
                f32x4 o;
                o.x = nslope * fabsf(d);
                o.y = nslope * fabsf(d - 1.0f);
                o.z = nslope * fabsf(d - 2.0f);
                o.w = nslope * fabsf(d - 3.0f);
                __builtin_nontemporal_store(o, p);

                o.x = nslope * fabsf(d2);
                o.y = nslope * fabsf(d2 - 1.0f);
                o.z = nslope * fabsf(d2 - 2.0f);
                o.w = nslope * fabsf(d2 - 3.0f);
                __builtin_nontemporal_store(o, p + 256);

                d += 1.0f; d2 += 1.0f;
                p += 512;                                     // next row
            }
            return;
        }
    }

    // Generic fallback: grid-stride scalar, any S.
    const unsigned int stride = gridDim.x * blockDim.x;
    for (unsigned int e = blockIdx.x * blockDim.x + threadIdx.x;
         e < n_total; e += stride) {
        unsigned int j   = e % S;
        unsigned int row = e / S;
        unsigned int i   = row % S;
        unsigned int h   = (row / S) % NUM_HEADS;
        out[e] = -slopes[h] * (float)abs((int)i - (int)j);
    }
}

extern "C" void kernel_launch(void* const* d_in, const int* in_sizes, int n_in,
                              void* d_out, int out_size, void* d_ws, size_t ws_size,
                              hipStream_t stream) {
    const float* slopes = (const float*)d_in[0];
    const int*   seq_p  = (const int*)d_in[1];
    float*       out    = (float*)d_out;

    const unsigned int n = (unsigned int)out_size;

    // 2048 blocks x 256 thr = 8192 waves = exact residency on 256 CUs.
    const int block = 256;
    unsigned int grid = 2048u;

    alibi_bias_kernel<<<dim3(grid), dim3(block), 0, stream>>>(slopes, seq_p, out, n);
}